// Round 1
// baseline (445.202 us; speedup 1.0000x reference)
//
#include <hip/hip_runtime.h>
#include <hip/hip_bf16.h>
#include <math.h>

#define B_SZ   1024
#define NROW   2048      // 2B
#define D_K    16384     // 128*128
#define TEMP_INV 2.0f    // 1/0.5

typedef short bf16x8 __attribute__((ext_vector_type(8)));
typedef float f32x4  __attribute__((ext_vector_type(4)));

typedef __attribute__((address_space(1))) unsigned int GU32;
typedef __attribute__((address_space(3))) unsigned int LU32;

__device__ __forceinline__ void async16(const void* g, void* l) {
  __builtin_amdgcn_global_load_lds((GU32*)(g), (LU32*)(l), 16, 0, 0);
}

// ---------------------------------------------------------------------------
// Kernel 1: per-row normalization -> bf16 rn[2048][16384]
// One block per row b. Column n norm over m (stride-128), then row renorm.
// ---------------------------------------------------------------------------
__global__ __launch_bounds__(256) void norm_kernel(
    const float* __restrict__ emb_i, const float* __restrict__ emb_j,
    __hip_bfloat16* __restrict__ rn, float* __restrict__ denom,
    float* __restrict__ pos)
{
  const int b   = blockIdx.x;      // 0..2047
  const int n   = threadIdx.x;     // 0..127 (column)
  const int h   = threadIdx.y;     // 0..1   (m-half)
  const int tid = n + (h << 7);

  if (b == 0) {  // zero accumulators (ws re-poisoned each call)
    for (int k = tid; k < NROW; k += 256) { denom[k] = 0.f; pos[k] = 0.f; }
  }

  const float* src = (b < B_SZ) ? (emb_i + (size_t)b * D_K)
                                : (emb_j + (size_t)(b - B_SZ) * D_K);

  float vals[64];
  float ss = 0.f;
#pragma unroll
  for (int mm = 0; mm < 64; ++mm) {
    float v = src[(size_t)(h * 64 + mm) * 128 + n];
    vals[mm] = v;
    ss += v * v;
  }

  __shared__ float part[2][128];
  part[h][n] = ss;
  __syncthreads();
  const float css = part[0][n] + part[1][n];   // column sum of squares
  const float cn  = sqrtf(css);
  const float mcn = fmaxf(cn, 1e-12f);
  const float colz2 = css / (mcn * mcn);       // sumsq of normalized column (~1)

  // reduce colz2 over 128 columns: waves 0,1 are h==0 covering n=0..127
  float c = colz2;
#pragma unroll
  for (int off = 1; off < 64; off <<= 1) c += __shfl_xor(c, off);
  __shared__ float sred[4];
  if ((tid & 63) == 0) sred[tid >> 6] = c;
  __syncthreads();
  const float rowss = sred[0] + sred[1];
  const float scale = 1.f / (mcn * fmaxf(sqrtf(rowss), 1e-8f));

  __hip_bfloat16* dst = rn + (size_t)b * D_K;
#pragma unroll
  for (int mm = 0; mm < 64; ++mm) {
    dst[(size_t)(h * 64 + mm) * 128 + n] = __float2bfloat16(vals[mm] * scale);
  }
}

// ---------------------------------------------------------------------------
// Kernel 2: sim = rn @ rn^T (bf16 MFMA, m97 structure) + fused NT-Xent pieces
// 128x128 tile / block, 256 threads = 4 waves (2x2 of 64x64), BK=32.
// Epilogue: denom[i] += sum_j!=i exp(2*sim_ij); pos[i] = sim[i, i+-B].
// ---------------------------------------------------------------------------
__global__ __launch_bounds__(256) void gemm_loss_kernel(
    const __hip_bfloat16* __restrict__ rn,
    float* __restrict__ denom, float* __restrict__ pos)
{
  const int tI = blockIdx.x, tJ = blockIdx.y;
  const int t    = threadIdx.x;
  const int lane = t & 63;
  const int wave = t >> 6;
  const int wm = wave >> 1, wn = wave & 1;
  const int quad = lane >> 4, col = lane & 15;

  __shared__ __align__(16) short As[128 * 32];
  __shared__ __align__(16) short Bs[128 * 32];

  const short* rnS = (const short*)rn;
  // staging: thread t loads 16B: row = t>>2, kchunk = (t&3)*8  (issue0: rows 0-63)
  const short* aG = rnS + (size_t)(tI * 128 + (t >> 2)) * D_K + (t & 3) * 8;
  const short* bG = rnS + (size_t)(tJ * 128 + (t >> 2)) * D_K + (t & 3) * 8;
  short* aL0 = &As[t * 8];
  short* aL1 = &As[2048 + t * 8];
  short* bL0 = &Bs[t * 8];
  short* bL1 = &Bs[2048 + t * 8];
  const size_t half = (size_t)64 * D_K;

  f32x4 acc[4][4];
#pragma unroll
  for (int mi = 0; mi < 4; ++mi)
#pragma unroll
    for (int ni = 0; ni < 4; ++ni)
      acc[mi][ni] = (f32x4){0.f, 0.f, 0.f, 0.f};

  // fragment read base: A[m=lane&15][k=quad*8+j] -> row-major [128][32] LDS
  const short* aLr = &As[(wm * 64 + col) * 32 + quad * 8];
  const short* bLr = &Bs[(wn * 64 + col) * 32 + quad * 8];

  for (int k0 = 0; k0 < D_K; k0 += 32) {
    __syncthreads();                      // previous compute done before overwrite
    async16(aG + k0, aL0);
    async16(aG + half + k0, aL1);
    async16(bG + k0, bL0);
    async16(bG + half + k0, bL1);
    __syncthreads();                      // drains vmcnt before LDS reads

    bf16x8 af[4], bf[4];
#pragma unroll
    for (int mi = 0; mi < 4; ++mi) af[mi] = *(const bf16x8*)(aLr + mi * 16 * 32);
#pragma unroll
    for (int ni = 0; ni < 4; ++ni) bf[ni] = *(const bf16x8*)(bLr + ni * 16 * 32);
#pragma unroll
    for (int mi = 0; mi < 4; ++mi)
#pragma unroll
      for (int ni = 0; ni < 4; ++ni)
        acc[mi][ni] = __builtin_amdgcn_mfma_f32_16x16x32_bf16(
            af[mi], bf[ni], acc[mi][ni], 0, 0, 0);
  }

  // Epilogue: C/D layout col=lane&15, row=quad*4+reg
  const int iB = tI * 128 + wm * 64;
  const int jB = tJ * 128 + wn * 64;
#pragma unroll
  for (int mi = 0; mi < 4; ++mi) {
#pragma unroll
    for (int reg = 0; reg < 4; ++reg) {
      const int i = iB + mi * 16 + quad * 4 + reg;
      float s = 0.f;
#pragma unroll
      for (int ni = 0; ni < 4; ++ni) {
        const int j = jB + ni * 16 + col;
        const float v = acc[mi][ni][reg];
        if (j == i + B_SZ || j == i - B_SZ) pos[i] = v;  // positives (each once)
        s += (i == j) ? 0.f : __expf(TEMP_INV * v);
      }
      // reduce the 16 columns of this quad
#pragma unroll
      for (int off = 1; off < 16; off <<= 1) s += __shfl_xor(s, off);
      if (col == 0) atomicAdd(&denom[i], s);
    }
  }
}

// ---------------------------------------------------------------------------
// Kernel 3: loss = (1/2B) * sum_i [ log(denom_i) - 2*pos_i ]
// ---------------------------------------------------------------------------
__global__ __launch_bounds__(256) void finalize_kernel(
    const float* __restrict__ denom, const float* __restrict__ pos,
    float* __restrict__ out)
{
  const int t = threadIdx.x;
  float s = 0.f;
  for (int k = t; k < NROW; k += 256) s += logf(denom[k]) - TEMP_INV * pos[k];
#pragma unroll
  for (int off = 1; off < 64; off <<= 1) s += __shfl_xor(s, off);
  __shared__ float r[4];
  if ((t & 63) == 0) r[t >> 6] = s;
  __syncthreads();
  if (t == 0) out[0] = (r[0] + r[1] + r[2] + r[3]) * (1.0f / NROW);
}

extern "C" void kernel_launch(void* const* d_in, const int* in_sizes, int n_in,
                              void* d_out, int out_size, void* d_ws, size_t ws_size,
                              hipStream_t stream) {
  const float* emb_i = (const float*)d_in[0];
  const float* emb_j = (const float*)d_in[1];
  float* out = (float*)d_out;

  char* ws = (char*)d_ws;
  __hip_bfloat16* rn = (__hip_bfloat16*)ws;                       // 64 MB
  float* denom = (float*)(ws + (size_t)NROW * D_K * sizeof(short)); // 8 KB
  float* pos   = denom + NROW;                                      // 8 KB

  norm_kernel<<<dim3(NROW), dim3(128, 2), 0, stream>>>(emb_i, emb_j, rn, denom, pos);
  gemm_loss_kernel<<<dim3(16, 16), dim3(256), 0, stream>>>(rn, denom, pos);
  finalize_kernel<<<1, 256, 0, stream>>>(denom, pos, out);
}

// Round 3
// 372.980 us; speedup vs baseline: 1.1936x; 1.1936x over previous
//
#include <hip/hip_runtime.h>
#include <hip/hip_bf16.h>
#include <math.h>

#define B_SZ   1024
#define NROW   2048      // 2B
#define D_K    16384     // 128*128
#define TEMP_INV 2.0f    // 1/0.5
#define SPLIT  4
#define KSEG   (D_K / SPLIT)

typedef short bf16x8 __attribute__((ext_vector_type(8)));
typedef float f32x4  __attribute__((ext_vector_type(4)));
typedef unsigned short u16x4 __attribute__((ext_vector_type(4)));

typedef __attribute__((address_space(1))) unsigned int GU32;
typedef __attribute__((address_space(3))) unsigned int LU32;

__device__ __forceinline__ void async16(const void* g, void* l) {
  __builtin_amdgcn_global_load_lds((GU32*)(g), (LU32*)(l), 16, 0, 0);
}

// fp32 -> bf16 bits, round-to-nearest-even (finite inputs)
__device__ __forceinline__ unsigned short f2bf(float f) {
  unsigned int u = __float_as_uint(f);
  u += 0x7fffu + ((u >> 16) & 1u);
  return (unsigned short)(u >> 16);
}

// ---------------------------------------------------------------------------
// Kernel 1: per-row normalize -> bf16 rn[2048][16384]; also zero sim (16 MB).
// Block = row b, 256 threads. Thread t: cols 4*(t&31)..+3, rows (t>>5)*16..+15.
// ---------------------------------------------------------------------------
__global__ __launch_bounds__(256) void norm_kernel(
    const float* __restrict__ emb_i, const float* __restrict__ emb_j,
    __hip_bfloat16* __restrict__ rn, float* __restrict__ sim)
{
  const int b = blockIdx.x;
  const int t = threadIdx.x;
  const int c = t & 31;        // column group (4 cols)
  const int g = t >> 5;        // row group (16 rows)

  // stripe-zero sim: 2048 blocks x 256 thr x 2 float4 = 16 MB exactly
  {
    f32x4* sz = (f32x4*)sim + (size_t)b * 512 + t * 2;
    sz[0] = (f32x4){0.f, 0.f, 0.f, 0.f};
    sz[1] = (f32x4){0.f, 0.f, 0.f, 0.f};
  }

  const float* src = (b < B_SZ) ? (emb_i + (size_t)b * D_K)
                                : (emb_j + (size_t)(b - B_SZ) * D_K);

  f32x4 vals[16];
  f32x4 ss = (f32x4){0.f, 0.f, 0.f, 0.f};
#pragma unroll
  for (int mm = 0; mm < 16; ++mm) {
    f32x4 v = *(const f32x4*)(src + (size_t)(g * 16 + mm) * 128 + c * 4);
    vals[mm] = v;
    ss += v * v;
  }

  __shared__ f32x4 part[8][32];
  part[g][c] = ss;
  __syncthreads();
  f32x4 css = part[0][c];
#pragma unroll
  for (int gg = 1; gg < 8; ++gg) css += part[gg][c];

  f32x4 mcn, colz2;
#pragma unroll
  for (int k = 0; k < 4; ++k) {
    mcn[k] = fmaxf(sqrtf(css[k]), 1e-12f);
    colz2[k] = css[k] / (mcn[k] * mcn[k]);
  }
  // each wave holds every c twice -> wave sum = 2 * rowss
  float s = colz2[0] + colz2[1] + colz2[2] + colz2[3];
#pragma unroll
  for (int off = 1; off < 64; off <<= 1) s += __shfl_xor(s, off);
  const float rowss = 0.5f * s;
  const float rowfac = fmaxf(sqrtf(rowss), 1e-8f);

  f32x4 scale;
#pragma unroll
  for (int k = 0; k < 4; ++k) scale[k] = 1.f / (mcn[k] * rowfac);

  __hip_bfloat16* dst = rn + (size_t)b * D_K;
#pragma unroll
  for (int mm = 0; mm < 16; ++mm) {
    f32x4 sv = vals[mm] * scale;
    u16x4 o;
#pragma unroll
    for (int k = 0; k < 4; ++k)
      o[k] = f2bf(sv[k]);
    *(u16x4*)(dst + (size_t)(g * 16 + mm) * 128 + c * 4) = o;
  }
}

// ---------------------------------------------------------------------------
// Kernel 2: sim += rn @ rn^T  (bf16 MFMA, 128x128 tile, BK=32, split-K=4)
// Grid (16,16,4); 256 threads = 4 waves (2x2 of 64x64 subtiles).
// ---------------------------------------------------------------------------
__global__ __launch_bounds__(256) void gemm_sim_kernel(
    const __hip_bfloat16* __restrict__ rn, float* __restrict__ sim)
{
  const int tI = blockIdx.x, tJ = blockIdx.y;
  const int kBase = blockIdx.z * KSEG;
  const int t    = threadIdx.x;
  const int lane = t & 63;
  const int wave = t >> 6;
  const int wm = wave >> 1, wn = wave & 1;
  const int quad = lane >> 4, col = lane & 15;

  __shared__ __align__(16) short As[128 * 32];
  __shared__ __align__(16) short Bs[128 * 32];

  const short* rnS = (const short*)rn;
  const short* aG = rnS + (size_t)(tI * 128 + (t >> 2)) * D_K + kBase + (t & 3) * 8;
  const short* bG = rnS + (size_t)(tJ * 128 + (t >> 2)) * D_K + kBase + (t & 3) * 8;
  short* aL0 = &As[t * 8];
  short* aL1 = &As[2048 + t * 8];
  short* bL0 = &Bs[t * 8];
  short* bL1 = &Bs[2048 + t * 8];
  const size_t half = (size_t)64 * D_K;

  f32x4 acc[4][4];
#pragma unroll
  for (int mi = 0; mi < 4; ++mi)
#pragma unroll
    for (int ni = 0; ni < 4; ++ni)
      acc[mi][ni] = (f32x4){0.f, 0.f, 0.f, 0.f};

  const short* aLr = &As[(wm * 64 + col) * 32 + quad * 8];
  const short* bLr = &Bs[(wn * 64 + col) * 32 + quad * 8];

  for (int k0 = 0; k0 < KSEG; k0 += 32) {
    __syncthreads();
    async16(aG + k0, aL0);
    async16(aG + half + k0, aL1);
    async16(bG + k0, bL0);
    async16(bG + half + k0, bL1);
    __syncthreads();

    bf16x8 af[4], bf[4];
#pragma unroll
    for (int mi = 0; mi < 4; ++mi) af[mi] = *(const bf16x8*)(aLr + mi * 16 * 32);
#pragma unroll
    for (int ni = 0; ni < 4; ++ni) bf[ni] = *(const bf16x8*)(bLr + ni * 16 * 32);
#pragma unroll
    for (int mi = 0; mi < 4; ++mi)
#pragma unroll
      for (int ni = 0; ni < 4; ++ni)
        acc[mi][ni] = __builtin_amdgcn_mfma_f32_16x16x32_bf16(
            af[mi], bf[ni], acc[mi][ni], 0, 0, 0);
  }

  // C/D layout: col=lane&15, row=quad*4+reg
  const int iB = tI * 128 + wm * 64;
  const int jB = tJ * 128 + wn * 64;
#pragma unroll
  for (int mi = 0; mi < 4; ++mi) {
#pragma unroll
    for (int reg = 0; reg < 4; ++reg) {
      const int i = iB + mi * 16 + quad * 4 + reg;
#pragma unroll
      for (int ni = 0; ni < 4; ++ni) {
        const int j = jB + ni * 16 + col;
        atomicAdd(&sim[(size_t)i * NROW + j], acc[mi][ni][reg]);
      }
    }
  }
}

// ---------------------------------------------------------------------------
// Kernel 3: per-row NT-Xent term: rowval[i] = log(sum_{j!=i} e^{2 sim_ij}) - 2 pos_i
// ---------------------------------------------------------------------------
__global__ __launch_bounds__(256) void loss_kernel(
    const float* __restrict__ sim, float* __restrict__ rowval)
{
  const int i = blockIdx.x;
  const int t = threadIdx.x;
  const float* row = sim + (size_t)i * NROW;

  float s = 0.f;
#pragma unroll
  for (int rep = 0; rep < 2; ++rep) {
    const int j4 = (t + rep * 256) * 4;
    f32x4 v = *(const f32x4*)(row + j4);
#pragma unroll
    for (int k = 0; k < 4; ++k)
      s += (j4 + k == i) ? 0.f : __expf(TEMP_INV * v[k]);
  }
#pragma unroll
  for (int off = 1; off < 64; off <<= 1) s += __shfl_xor(s, off);
  __shared__ float r[4];
  if ((t & 63) == 0) r[t >> 6] = s;
  __syncthreads();
  if (t == 0) {
    const float denom = r[0] + r[1] + r[2] + r[3];
    const int jp = (i < B_SZ) ? i + B_SZ : i - B_SZ;
    rowval[i] = logf(denom) - TEMP_INV * row[jp];
  }
}

// ---------------------------------------------------------------------------
// Kernel 4: loss = mean(rowval)
// ---------------------------------------------------------------------------
__global__ __launch_bounds__(256) void finalize_kernel(
    const float* __restrict__ rowval, float* __restrict__ out)
{
  const int t = threadIdx.x;
  float s = 0.f;
  for (int k = t; k < NROW; k += 256) s += rowval[k];
#pragma unroll
  for (int off = 1; off < 64; off <<= 1) s += __shfl_xor(s, off);
  __shared__ float r[4];
  if ((t & 63) == 0) r[t >> 6] = s;
  __syncthreads();
  if (t == 0) out[0] = (r[0] + r[1] + r[2] + r[3]) * (1.0f / NROW);
}

extern "C" void kernel_launch(void* const* d_in, const int* in_sizes, int n_in,
                              void* d_out, int out_size, void* d_ws, size_t ws_size,
                              hipStream_t stream) {
  const float* emb_i = (const float*)d_in[0];
  const float* emb_j = (const float*)d_in[1];
  float* out = (float*)d_out;

  char* ws = (char*)d_ws;
  __hip_bfloat16* rn = (__hip_bfloat16*)ws;                          // 64 MB
  float* sim    = (float*)(ws + (size_t)NROW * D_K * sizeof(short)); // 16 MB
  float* rowval = sim + (size_t)NROW * NROW;                         // 8 KB

  norm_kernel<<<dim3(NROW), dim3(256), 0, stream>>>(emb_i, emb_j, rn, sim);
  gemm_sim_kernel<<<dim3(16, 16, SPLIT), dim3(256), 0, stream>>>(rn, sim);
  loss_kernel<<<dim3(NROW), dim3(256), 0, stream>>>(sim, rowval);
  finalize_kernel<<<1, 256, 0, stream>>>(rowval, out);
}